// Round 2
// baseline (496.607 us; speedup 1.0000x reference)
//
#include <hip/hip_runtime.h>

// RouterModel: top-1-of-2 softmax router with dense dispatch.
//   score = softmax(x @ W); path = argmax(score) (tie -> 0)
//   x0 = x*g0, x1 = x*g1, xc = x*(g0+g1)  with exactly one of g0,g1 nonzero.
//
// Two-kernel split:
//   A) gate_kernel: one wave per token, reads x (134 MB, allocates in L3),
//      computes (g0,g1,gc) -> d_ws (512 KB).
//   B) scatter_kernel: pure stream, 1 float4 load (L3-hit) + 3 nontemporal
//      float4 stores (403 MB HBM, no L3 pollution). Copy-kernel shaped.

constexpr int       kN  = 32768;
constexpr int       kD  = 1024;
constexpr long long kND = (long long)kN * kD;
constexpr int       kV  = (int)(kND / 4);      // 8,388,608 float4s per output

typedef float f4 __attribute__((ext_vector_type(4)));

__global__ __launch_bounds__(256) void gate_kernel(
    const float* __restrict__ x, const float* __restrict__ W,
    f4* __restrict__ gates)
{
    const int wave = threadIdx.x >> 6;
    const int lane = threadIdx.x & 63;
    const int t    = blockIdx.x * 4 + wave;     // token id, grid sized exactly

    const f4* __restrict__ row4 = (const f4*)(x + (long long)t * kD);
    const f4* __restrict__ W4   = (const f4*)W;  // interleaved [D,2]

    float s0 = 0.f, s1 = 0.f;
#pragma unroll
    for (int j = 0; j < 4; ++j) {
        const int idx = lane + j * 64;          // 0..255 float4s of the row
        const f4 v  = row4[idx];
        const f4 wa = W4[2 * idx];              // {W0[d],W1[d],W0[d+1],W1[d+1]}
        const f4 wb = W4[2 * idx + 1];
        s0 += v.x * wa.x + v.y * wa.z + v.z * wb.x + v.w * wb.z;
        s1 += v.x * wa.y + v.y * wa.w + v.z * wb.y + v.w * wb.w;
    }
#pragma unroll
    for (int off = 32; off >= 1; off >>= 1) {   // 64-lane butterfly
        s0 += __shfl_xor(s0, off, 64);
        s1 += __shfl_xor(s1, off, 64);
    }
    if (lane == 0) {
        const float m   = fmaxf(s0, s1);
        const float e0  = __expf(s0 - m);
        const float e1  = __expf(s1 - m);
        const float inv = 1.f / (e0 + e1);
        const float p0  = e0 * inv;
        const float p1  = e1 * inv;
        const int path  = (s1 > s0) ? 1 : 0;    // tie -> 0, matches jnp.argmax
        const float g0  = (path == 0) ? p0 : 0.f;
        const float g1  = (path == 1) ? p1 : 0.f;
        f4 g; g.x = g0; g.y = g1; g.z = g0 + g1; g.w = 0.f;
        gates[t] = g;
    }
}

// Grid: 8192 blocks x 256 threads, 4 float4s per thread (exact cover of kV).
__global__ __launch_bounds__(256) void scatter_kernel(
    const float* __restrict__ x, const f4* __restrict__ gates,
    float* __restrict__ out)
{
    const int base = blockIdx.x * 256 + threadIdx.x;
    const f4* __restrict__ x4 = (const f4*)x;
    f4* __restrict__ o0 = (f4*)out;
    f4* __restrict__ o1 = (f4*)(out + kND);
    f4* __restrict__ oc = (f4*)(out + 2 * kND);

#pragma unroll
    for (int k = 0; k < 4; ++k) {
        const int i   = base + k * (8192 * 256);
        const int row = i >> 8;                 // 256 float4s per row
        const f4 g = gates[row];                // wave-uniform -> broadcast hit
        const f4 v = x4[i];                     // L3-resident after gate_kernel
        f4 a, b, c;
        a.x = v.x * g.x; a.y = v.y * g.x; a.z = v.z * g.x; a.w = v.w * g.x;
        b.x = v.x * g.y; b.y = v.y * g.y; b.z = v.z * g.y; b.w = v.w * g.y;
        c.x = v.x * g.z; c.y = v.y * g.z; c.z = v.z * g.z; c.w = v.w * g.z;
        __builtin_nontemporal_store(a, &o0[i]); // outputs never re-read:
        __builtin_nontemporal_store(b, &o1[i]); // don't evict x from L3
        __builtin_nontemporal_store(c, &oc[i]);
    }
}

extern "C" void kernel_launch(void* const* d_in, const int* in_sizes, int n_in,
                              void* d_out, int out_size, void* d_ws, size_t ws_size,
                              hipStream_t stream)
{
    const float* x = (const float*)d_in[0];   // [N, D] fp32
    const float* W = (const float*)d_in[1];   // [D, 2] fp32
    float* out     = (float*)d_out;           // x0 | x1 | xc, each [N, D]
    f4* gates      = (f4*)d_ws;               // [N] (g0, g1, gc, 0) = 512 KB

    gate_kernel   <<<kN / 4, 256, 0, stream>>>(x, W, gates);
    scatter_kernel<<<8192,   256, 0, stream>>>(x, gates, out);
}